// Round 1
// baseline (3010.575 us; speedup 1.0000x reference)
//
#include <hip/hip_runtime.h>
#include <math.h>

constexpr int IN_DIM = 256;
constexpr int HID    = 128;
constexpr int OUT_DIM = 64;

// ---------------------------------------------------------------------------
// fc1: h1[N,128] = feat[N,256] @ W1[256,128] + b1
// Block: 256 threads, computes 64 rows x 128 cols.
// Thread (tx=t&31, ty=t>>5) computes 8 rows x 4 cols.
// LDS: feat tile [64 rows][64 k] (16KB) + W1 tile [64 k][128 c] (32KB).
// Compute reads of sF are 2-addresses-per-wave broadcasts (conflict-free);
// sW reads are row-contiguous float4 (conflict-free).
// ---------------------------------------------------------------------------
__global__ __launch_bounds__(256) void fc1_kernel(const float* __restrict__ feat,
                                                  const float* __restrict__ W1,
                                                  const float* __restrict__ b1,
                                                  float* __restrict__ h1, int N)
{
    __shared__ float sF[64][64];    // [row][k]
    __shared__ float sW[64][128];   // [k][c]
    const int t   = threadIdx.x;
    const int tx  = t & 31;         // col group: cols tx*4 .. tx*4+3
    const int ty  = t >> 5;         // row group: rows ty*8 .. ty*8+7
    const int row0 = blockIdx.x * 64;

    float4 acc[8];
#pragma unroll
    for (int i = 0; i < 8; ++i) acc[i] = make_float4(0.f, 0.f, 0.f, 0.f);

    for (int kc = 0; kc < IN_DIM; kc += 64) {
        // stage features tile: 64x64 floats = 1024 float4, 4 per thread
#pragma unroll
        for (int i = 0; i < 4; ++i) {
            int idx = t + i * 256;          // 0..1023
            int r   = idx >> 4;             // /16 float4-per-row
            int k4  = idx & 15;
            int grow = row0 + r;
            float4 v = make_float4(0.f, 0.f, 0.f, 0.f);
            if (grow < N)
                v = *(const float4*)&feat[(size_t)grow * IN_DIM + kc + k4 * 4];
            *(float4*)&sF[r][k4 * 4] = v;
        }
        // stage W1 tile: 64x128 floats = 2048 float4, 8 per thread
#pragma unroll
        for (int i = 0; i < 8; ++i) {
            int idx = t + i * 256;          // 0..2047
            int k   = idx >> 5;             // /32 float4-per-row
            int c4  = idx & 31;
            *(float4*)&sW[k][c4 * 4] = *(const float4*)&W1[(size_t)(kc + k) * HID + c4 * 4];
        }
        __syncthreads();
#pragma unroll 8
        for (int k = 0; k < 64; ++k) {
            float4 w = *(const float4*)&sW[k][tx * 4];
#pragma unroll
            for (int i = 0; i < 8; ++i) {
                float f = sF[ty * 8 + i][k];
                acc[i].x += f * w.x;
                acc[i].y += f * w.y;
                acc[i].z += f * w.z;
                acc[i].w += f * w.w;
            }
        }
        __syncthreads();
    }

    float4 bb = *(const float4*)&b1[tx * 4];
#pragma unroll
    for (int i = 0; i < 8; ++i) {
        int grow = row0 + ty * 8 + i;
        if (grow < N) {
            float4 o;
            o.x = acc[i].x + bb.x;
            o.y = acc[i].y + bb.y;
            o.z = acc[i].z + bb.z;
            o.w = acc[i].w + bb.w;
            *(float4*)&h1[(size_t)grow * HID + tx * 4] = o;
        }
    }
}

// ---------------------------------------------------------------------------
// spmm: h2[r] += v * h1[c] for each edge. One wave per edge per iteration;
// lane handles 2 hid dims (float2 gather, 2 atomicAdds).
// ---------------------------------------------------------------------------
__global__ __launch_bounds__(256) void spmm_kernel(const int* __restrict__ erow,
                                                   const int* __restrict__ ecol,
                                                   const float* __restrict__ eval,
                                                   const float* __restrict__ h1,
                                                   float* __restrict__ h2, int E)
{
    const int lane   = threadIdx.x & 63;
    const int wave   = (blockIdx.x * blockDim.x + threadIdx.x) >> 6;
    const int nwaves = (gridDim.x * blockDim.x) >> 6;
    for (int e = wave; e < E; e += nwaves) {
        int   r = erow[e];
        int   c = ecol[e];
        float v = eval[e];
        float2 hv = *(const float2*)&h1[(size_t)c * HID + lane * 2];
        atomicAdd(&h2[(size_t)r * HID + lane * 2    ], v * hv.x);
        atomicAdd(&h2[(size_t)r * HID + lane * 2 + 1], v * hv.y);
    }
}

// ---------------------------------------------------------------------------
// fc2 + bias + relu(input) + log_softmax, fused. One wave per row; lane = col.
// W2 (128x64 = 32KB) staged in LDS once per block.
// ---------------------------------------------------------------------------
__global__ __launch_bounds__(256) void fc2_kernel(const float* __restrict__ h2,
                                                  const float* __restrict__ W2,
                                                  const float* __restrict__ b2,
                                                  float* __restrict__ out, int N)
{
    __shared__ float sW[HID][OUT_DIM];   // 32 KB
    const int t = threadIdx.x;
#pragma unroll
    for (int i = 0; i < 8; ++i) {
        int idx = t + i * 256;           // 0..2047 float4 slots
        int k   = idx >> 4;              // 16 float4 per row of 64
        int c4  = idx & 15;
        *(float4*)&sW[k][c4 * 4] = *(const float4*)&W2[(size_t)k * OUT_DIM + c4 * 4];
    }
    __syncthreads();

    const int lane = t & 63;
    const int w    = t >> 6;             // wave id in block (0..3)
    const float b  = b2[lane];

    for (int r = blockIdx.x * 4 + w; r < N; r += gridDim.x * 4) {
        float acc = 0.f;
        const float* hrow = &h2[(size_t)r * HID];
#pragma unroll 8
        for (int k = 0; k < HID; ++k) {
            float x = hrow[k];               // wave-broadcast load
            x = x > 0.f ? x : 0.f;           // relu
            acc += x * sW[k][lane];
        }
        acc += b;
        // log_softmax over 64 lanes (= 64 cols)
        float m = acc;
#pragma unroll
        for (int o = 32; o > 0; o >>= 1) m = fmaxf(m, __shfl_xor(m, o));
        float ex = __expf(acc - m);
        float s  = ex;
#pragma unroll
        for (int o = 32; o > 0; o >>= 1) s += __shfl_xor(s, o);
        out[(size_t)r * OUT_DIM + lane] = acc - m - __logf(s);
    }
}

extern "C" void kernel_launch(void* const* d_in, const int* in_sizes, int n_in,
                              void* d_out, int out_size, void* d_ws, size_t ws_size,
                              hipStream_t stream) {
    const float* feat = (const float*)d_in[0];
    const int*   erow = (const int*)d_in[1];
    const int*   ecol = (const int*)d_in[2];
    const float* eval = (const float*)d_in[3];
    const float* W1   = (const float*)d_in[4];
    const float* b1   = (const float*)d_in[5];
    const float* W2   = (const float*)d_in[6];
    const float* b2   = (const float*)d_in[7];
    float*       out  = (float*)d_out;

    const int N = in_sizes[0] / IN_DIM;
    const int E = in_sizes[1];

    float* h1 = (float*)d_ws;                       // [N, HID]
    float* h2 = h1 + (size_t)N * HID;               // [N, HID]

    hipMemsetAsync(h2, 0, (size_t)N * HID * sizeof(float), stream);

    fc1_kernel<<<(N + 63) / 64, 256, 0, stream>>>(feat, W1, b1, h1, N);
    spmm_kernel<<<8192, 256, 0, stream>>>(erow, ecol, eval, h1, h2, E);
    fc2_kernel<<<(N + 3) / 4, 256, 0, stream>>>(h2, W2, b2, out, N);
}

// Round 2
// 1003.540 us; speedup vs baseline: 3.0000x; 3.0000x over previous
//
#include <hip/hip_runtime.h>
#include <math.h>

constexpr int IN_DIM = 256;
constexpr int HID    = 128;
constexpr int OUT_DIM = 64;

// ---------------------------------------------------------------------------
// fc1: h1[N,128] = feat[N,256] @ W1[256,128] + b1   (unchanged from R1)
// ---------------------------------------------------------------------------
__global__ __launch_bounds__(256) void fc1_kernel(const float* __restrict__ feat,
                                                  const float* __restrict__ W1,
                                                  const float* __restrict__ b1,
                                                  float* __restrict__ h1, int N)
{
    __shared__ float sF[64][64];    // [row][k]
    __shared__ float sW[64][128];   // [k][c]
    const int t   = threadIdx.x;
    const int tx  = t & 31;
    const int ty  = t >> 5;
    const int row0 = blockIdx.x * 64;

    float4 acc[8];
#pragma unroll
    for (int i = 0; i < 8; ++i) acc[i] = make_float4(0.f, 0.f, 0.f, 0.f);

    for (int kc = 0; kc < IN_DIM; kc += 64) {
#pragma unroll
        for (int i = 0; i < 4; ++i) {
            int idx = t + i * 256;
            int r   = idx >> 4;
            int k4  = idx & 15;
            int grow = row0 + r;
            float4 v = make_float4(0.f, 0.f, 0.f, 0.f);
            if (grow < N)
                v = *(const float4*)&feat[(size_t)grow * IN_DIM + kc + k4 * 4];
            *(float4*)&sF[r][k4 * 4] = v;
        }
#pragma unroll
        for (int i = 0; i < 8; ++i) {
            int idx = t + i * 256;
            int k   = idx >> 5;
            int c4  = idx & 31;
            *(float4*)&sW[k][c4 * 4] = *(const float4*)&W1[(size_t)(kc + k) * HID + c4 * 4];
        }
        __syncthreads();
#pragma unroll 8
        for (int k = 0; k < 64; ++k) {
            float4 w = *(const float4*)&sW[k][tx * 4];
#pragma unroll
            for (int i = 0; i < 8; ++i) {
                float f = sF[ty * 8 + i][k];
                acc[i].x += f * w.x;
                acc[i].y += f * w.y;
                acc[i].z += f * w.z;
                acc[i].w += f * w.w;
            }
        }
        __syncthreads();
    }

    float4 bb = *(const float4*)&b1[tx * 4];
#pragma unroll
    for (int i = 0; i < 8; ++i) {
        int grow = row0 + ty * 8 + i;
        if (grow < N) {
            float4 o;
            o.x = acc[i].x + bb.x;
            o.y = acc[i].y + bb.y;
            o.z = acc[i].z + bb.z;
            o.w = acc[i].w + bb.w;
            *(float4*)&h1[(size_t)grow * HID + tx * 4] = o;
        }
    }
}

// ---------------------------------------------------------------------------
// CSR build: histogram -> 3-phase exclusive scan -> scatter (counting sort)
// ---------------------------------------------------------------------------
__global__ __launch_bounds__(256) void hist_kernel(const int* __restrict__ erow,
                                                   int* __restrict__ cnt, int E)
{
    int i = blockIdx.x * blockDim.x + threadIdx.x;
    if (i < E) atomicAdd(&cnt[erow[i]], 1);
}

// Phase 1: per-block (2048-element chunk) sums
__global__ __launch_bounds__(256) void scan_sums(const int* __restrict__ cnt,
                                                 int* __restrict__ bsum, int N)
{
    __shared__ int red[256];
    const int b = blockIdx.x, t = threadIdx.x;
    const int base = b * 2048;
    int s = 0;
#pragma unroll
    for (int i = 0; i < 8; ++i) {
        int idx = base + t * 8 + i;
        if (idx < N) s += cnt[idx];
    }
    red[t] = s; __syncthreads();
    for (int o = 128; o > 0; o >>= 1) {
        if (t < o) red[t] += red[t + o];
        __syncthreads();
    }
    if (t == 0) bsum[b] = red[0];
}

// Phase 2: exclusive scan of block sums (nb <= 64, single wave)
__global__ __launch_bounds__(64) void scan_offsets(const int* __restrict__ bsum,
                                                   int* __restrict__ boff, int nb)
{
    int lane = threadIdx.x;
    int own = (lane < nb) ? bsum[lane] : 0;
    int v = own;
#pragma unroll
    for (int o = 1; o < 64; o <<= 1) {
        int u = __shfl_up(v, o);
        if (lane >= o) v += u;
    }
    if (lane < nb) boff[lane] = v - own;   // exclusive
}

// Phase 3: full exclusive scan -> rowStart[0..N], and init cursor = rowStart
__global__ __launch_bounds__(256) void scan_final(const int* __restrict__ cnt,
                                                  const int* __restrict__ boff,
                                                  int* __restrict__ rowStart,
                                                  int* __restrict__ cursor, int N)
{
    __shared__ int tsum[256];
    const int b = blockIdx.x, t = threadIdx.x;
    const int base = b * 2048;
    int loc[8]; int s = 0;
#pragma unroll
    for (int i = 0; i < 8; ++i) {
        int idx = base + t * 8 + i;
        loc[i] = (idx < N) ? cnt[idx] : 0;
        s += loc[i];
    }
    tsum[t] = s; __syncthreads();
    for (int o = 1; o < 256; o <<= 1) {
        int v = tsum[t];
        int u = (t >= o) ? tsum[t - o] : 0;
        __syncthreads();
        tsum[t] = v + u;
        __syncthreads();
    }
    int run = tsum[t] - s + boff[b];       // exclusive prefix for this thread
#pragma unroll
    for (int i = 0; i < 8; ++i) {
        int idx = base + t * 8 + i;
        if (idx < N) {
            rowStart[idx] = run;
            cursor[idx]   = run;
            run += loc[i];
            if (idx == N - 1) rowStart[N] = run;
        }
    }
}

__global__ __launch_bounds__(256) void scatter_kernel(const int* __restrict__ erow,
                                                      const int* __restrict__ ecol,
                                                      const float* __restrict__ eval,
                                                      int* __restrict__ cursor,
                                                      int2* __restrict__ sorted, int E)
{
    int i = blockIdx.x * blockDim.x + threadIdx.x;
    if (i < E) {
        int r = erow[i];
        int p = atomicAdd(&cursor[r], 1);
        sorted[p] = make_int2(ecol[i], __float_as_int(eval[i]));
    }
}

// ---------------------------------------------------------------------------
// spmm over CSR: one wave per row, lane handles 2 hid dims, no atomics.
// ---------------------------------------------------------------------------
__global__ __launch_bounds__(256) void spmm_csr(const int* __restrict__ rowStart,
                                                const int2* __restrict__ sorted,
                                                const float* __restrict__ h1,
                                                float* __restrict__ h2, int N)
{
    const int lane = threadIdx.x & 63;
    const int w    = (blockIdx.x * blockDim.x + threadIdx.x) >> 6;
    const int nw   = (gridDim.x * blockDim.x) >> 6;
    for (int r = w; r < N; r += nw) {
        const int s = rowStart[r], e = rowStart[r + 1];
        float ax = 0.f, ay = 0.f;
        int j = s;
        for (; j + 3 < e; j += 4) {
            int2 e0 = sorted[j];
            int2 e1 = sorted[j + 1];
            int2 e2 = sorted[j + 2];
            int2 e3 = sorted[j + 3];
            float2 h0 = *(const float2*)&h1[(size_t)e0.x * HID + lane * 2];
            float2 g1 = *(const float2*)&h1[(size_t)e1.x * HID + lane * 2];
            float2 g2 = *(const float2*)&h1[(size_t)e2.x * HID + lane * 2];
            float2 g3 = *(const float2*)&h1[(size_t)e3.x * HID + lane * 2];
            float v0 = __int_as_float(e0.y), v1 = __int_as_float(e1.y);
            float v2 = __int_as_float(e2.y), v3 = __int_as_float(e3.y);
            ax += v0 * h0.x; ay += v0 * h0.y;
            ax += v1 * g1.x; ay += v1 * g1.y;
            ax += v2 * g2.x; ay += v2 * g2.y;
            ax += v3 * g3.x; ay += v3 * g3.y;
        }
        for (; j < e; ++j) {
            int2 ed = sorted[j];
            float v = __int_as_float(ed.y);
            float2 hv = *(const float2*)&h1[(size_t)ed.x * HID + lane * 2];
            ax += v * hv.x; ay += v * hv.y;
        }
        *(float2*)&h2[(size_t)r * HID + lane * 2] = make_float2(ax, ay);
    }
}

// ---------------------------------------------------------------------------
// fc2 + bias + relu(input) + log_softmax, fused (unchanged from R1)
// ---------------------------------------------------------------------------
__global__ __launch_bounds__(256) void fc2_kernel(const float* __restrict__ h2,
                                                  const float* __restrict__ W2,
                                                  const float* __restrict__ b2,
                                                  float* __restrict__ out, int N)
{
    __shared__ float sW[HID][OUT_DIM];   // 32 KB
    const int t = threadIdx.x;
#pragma unroll
    for (int i = 0; i < 8; ++i) {
        int idx = t + i * 256;
        int k   = idx >> 4;
        int c4  = idx & 15;
        *(float4*)&sW[k][c4 * 4] = *(const float4*)&W2[(size_t)k * OUT_DIM + c4 * 4];
    }
    __syncthreads();

    const int lane = t & 63;
    const int w    = t >> 6;
    const float b  = b2[lane];

    for (int r = blockIdx.x * 4 + w; r < N; r += gridDim.x * 4) {
        float acc = 0.f;
        const float* hrow = &h2[(size_t)r * HID];
#pragma unroll 8
        for (int k = 0; k < HID; ++k) {
            float x = hrow[k];
            x = x > 0.f ? x : 0.f;
            acc += x * sW[k][lane];
        }
        acc += b;
        float m = acc;
#pragma unroll
        for (int o = 32; o > 0; o >>= 1) m = fmaxf(m, __shfl_xor(m, o));
        float ex = __expf(acc - m);
        float s  = ex;
#pragma unroll
        for (int o = 32; o > 0; o >>= 1) s += __shfl_xor(s, o);
        out[(size_t)r * OUT_DIM + lane] = acc - m - __logf(s);
    }
}

extern "C" void kernel_launch(void* const* d_in, const int* in_sizes, int n_in,
                              void* d_out, int out_size, void* d_ws, size_t ws_size,
                              hipStream_t stream) {
    const float* feat = (const float*)d_in[0];
    const int*   erow = (const int*)d_in[1];
    const int*   ecol = (const int*)d_in[2];
    const float* eval = (const float*)d_in[3];
    const float* W1   = (const float*)d_in[4];
    const float* b1   = (const float*)d_in[5];
    const float* W2   = (const float*)d_in[6];
    const float* b2   = (const float*)d_in[7];
    float*       out  = (float*)d_out;

    const int N = in_sizes[0] / IN_DIM;
    const int E = in_sizes[1];

    // workspace layout
    float* h1       = (float*)d_ws;                       // N*HID floats   (51.2 MB)
    float* h2       = h1 + (size_t)N * HID;               // N*HID floats   (51.2 MB)
    int*   cnt      = (int*)(h2 + (size_t)N * HID);       // N ints         (400 KB)
    int*   rowStart = cnt + N;                            // N+1 ints
    int*   cursor   = rowStart + (N + 1);                 // N ints
    int*   bsum     = cursor + N;                         // 64 ints
    int*   boff     = bsum + 64;                          // 64 ints
    int2*  sorted   = (int2*)(boff + 64);                 // E int2         (25.6 MB)

    const int nb = (N + 2047) / 2048;                     // scan chunks (49)

    hipMemsetAsync(cnt, 0, (size_t)N * sizeof(int), stream);

    fc1_kernel<<<(N + 63) / 64, 256, 0, stream>>>(feat, W1, b1, h1, N);

    hist_kernel<<<(E + 255) / 256, 256, 0, stream>>>(erow, cnt, E);
    scan_sums<<<nb, 256, 0, stream>>>(cnt, bsum, N);
    scan_offsets<<<1, 64, 0, stream>>>(bsum, boff, nb);
    scan_final<<<nb, 256, 0, stream>>>(cnt, boff, rowStart, cursor, N);
    scatter_kernel<<<(E + 255) / 256, 256, 0, stream>>>(erow, ecol, eval, cursor, sorted, E);

    spmm_csr<<<(N + 3) / 4, 256, 0, stream>>>(rowStart, sorted, h1, h2, N);

    fc2_kernel<<<(N + 3) / 4, 256, 0, stream>>>(h2, W2, b2, out, N);
}